// Round 19
// baseline (1555.104 us; speedup 1.0000x reference)
//
#include <hip/hip_runtime.h>
#include <math.h>

// ---------------- problem constants ----------------
#define NB     64
#define SL     2048
#define NTOK   (NB*SL)
#define EMB_D  128
#define DMODEL 128
#define DIN    256
#define DST    16
#define NLAYER 4
#define SEG    64
#define NSEG   (SL/SEG)        // 32
#define L2E    1.4426950408889634f
#define LN2    0.6931471805599453f

typedef __bf16 bf16x8 __attribute__((ext_vector_type(8)));
typedef __bf16 bf16x4 __attribute__((ext_vector_type(4)));
typedef float  f32x4  __attribute__((ext_vector_type(4)));

// fixed small region (floats)
#define FIX_PL   ((size_t)0)
#define FIX_PM   (FIX_PL + 131072)
#define FIX_PD   (FIX_PM + 1024)
#define FIX_H1   (FIX_PD + 8192)
#define FIX_H2   (FIX_H1 + 32768)
#define FIX_WP   (FIX_H2 + 32768)
#define FIX_W2B  (FIX_WP + 65536)
#define FIX_WINB (FIX_W2B + 24576)
#define FIX_WOUTB (FIX_WINB + 131072)
#define FIX_END  (FIX_WOUTB + 65536)

// raw-instruction transcendentals
__device__ __forceinline__ float fexp2(float x){ return __builtin_amdgcn_exp2f(x); }
__device__ __forceinline__ float flog2(float x){ return __builtin_amdgcn_logf(x); }
__device__ __forceinline__ float frcp (float x){ return __builtin_amdgcn_rcpf(x); }
__device__ __forceinline__ float fast_exp(float x){ return fexp2(x*L2E); }
__device__ __forceinline__ float siluf(float v){ return v * frcp(1.f + fast_exp(-v)); }
__device__ __forceinline__ float softplusf(float a){
  return fmaxf(a,0.f) + flog2(1.f + fexp2(-fabsf(a)*L2E)) * LN2;
}
__device__ __forceinline__ unsigned short bfbits(float x){
  __bf16 b = (__bf16)x; return __builtin_bit_cast(unsigned short, b);
}
__device__ __forceinline__ unsigned int packdu(float dt, float u){
  return ((unsigned int)bfbits(u) << 16) | (unsigned int)bfbits(dt);
}

// exact-path state-pair macros (fallback only)
#define SPSA(hA,hB,q,s0,s1) { float eA=fexp2(dt*(-fast_exp(alog[d*DST+s0])*L2E)); \
                              hA=fmaf(eA,hA,du*q.x); \
                              float eB=fexp2(dt*(-fast_exp(alog[d*DST+s1])*L2E)); \
                              hB=fmaf(eB,hB,du*q.z); }
#define SPSY(hA,hB,q,s0,s1) { float eA=fexp2(dt*(-fast_exp(alog[d*DST+s0])*L2E)); \
                              hA=fmaf(eA,hA,du*q.x); y=fmaf(hA,q.y,y); \
                              float eB=fexp2(dt*(-fast_exp(alog[d*DST+s1])*L2E)); \
                              hB=fmaf(eB,hB,du*q.z); y=fmaf(hB,q.w,y); }

// power tree r^1..r^16 from r (depth 4)
#define POWTREE(r) \
  float r2=(r)*(r), r4=r2*r2, r8=r4*r4; \
  float r3=r2*(r), r5=r4*(r), r6=r4*r2, r7=r4*r3; \
  float r9=r8*(r), r10=r8*r2, r11=r8*r3, r12=r8*r4; \
  float r13=r8*r5, r14=r8*r6, r15=r8*r7, r16=r8*r8;

// ---------------- weight prep ----------------
__global__ void k_w2b(const float* __restrict__ cw, __bf16* __restrict__ w2){
  int g = blockIdx.x*256 + threadIdx.x;
  if (g >= 128*384) return;
  int d = g / 384, j = g % 384;
  int k = j >> 7, e = j & 127;
  w2[d*384 + k*128 + e] = (__bf16)cw[d*384 + e*3 + k];
}

__global__ void k_cvt(const float* __restrict__ src, __bf16* __restrict__ dst, int n){
  int i = blockIdx.x*256 + threadIdx.x;
  if (i < n) dst[i] = (__bf16)src[i];
}

__global__ void k_wprep(const float* __restrict__ xpw, __bf16* __restrict__ wp){
  int g = blockIdx.x*256 + threadIdx.x;      // 65536
  int l = g >> 14, rem = g & 16383;
  int n = rem >> 8, k = rem & 255;
  float v = 0.f;
  if (n < 8){
    v = xpw[(size_t)l*40*256 + n*256 + k];
  } else if (n < 40){
    int i = n - 8;
    int row = 8 + ((i&1)<<4) + (i>>1);
    v = xpw[(size_t)l*40*256 + row*256 + k];
  }
  wp[g] = (__bf16)v;
}

// ---------------- embed + BN into padded chunk buffer (fp32 scratch) ----------------
__global__ void k_embed(const int* __restrict__ tok, const float* __restrict__ emb,
                        const float* __restrict__ bnw, const float* __restrict__ bnb,
                        float* __restrict__ xp){
  int r = blockIdx.x;                 // CB*2050 rows
  int e = threadIdx.x;                // 128
  int b = r / 2050, tp = r % 2050;
  float v = 0.f;
  if (tp != 0 && tp != 2049){
    int t = tp - 1;
    int id = tok[(size_t)b*SL + t];
    float s = bnw[e] * rsqrtf(1.0f + 1e-5f);
    v = emb[(size_t)id*EMB_D + e] * s + bnb[e];
  }
  xp[(size_t)r*EMB_D + e] = v;
}

// ---------------- rmsnorm scale only (after front conv) ----------------
__global__ __launch_bounds__(256) void k_rmsscale(const float* __restrict__ x,
                                                  float* __restrict__ rs){
  int wv = threadIdx.x>>6, lane = threadIdx.x&63;
  size_t tok = (size_t)blockIdx.x*4 + wv;
  float2 v = *(const float2*)(x + tok*128 + lane*2);
  float ss = v.x*v.x + v.y*v.y;
  #pragma unroll
  for (int m=1;m<64;m<<=1) ss += __shfl_xor(ss, m);
  float r = rsqrtf(ss*(1.f/128.f) + 1e-5f);
  if (lane == 0) rs[tok] = r;
}

// ---------------- bf16 MFMA GEMM ----------------
// MODE 0: A fp32 (padded im2col rows), epi relu(+bias) -> out fp32
// MODE 1: A fp32 (x), staged *rs*nw; epi n<256 -> outb (xi bf16), else outz (gz bf16)
template<int MODE, int K, int N>
__global__ __launch_bounds__(256) void k_mgemm(
    const void* __restrict__ Av, const __bf16* __restrict__ Wb,
    const float* __restrict__ bias, const float* __restrict__ rsp,
    const float* __restrict__ nwp,
    float* __restrict__ out, __bf16* __restrict__ outb, __bf16* __restrict__ outz){
  __shared__ __bf16 As[128][40];
  __shared__ __bf16 Bs[128][40];
  const int tid  = threadIdx.x;
  const int wave = tid >> 6;
  const int lane = tid & 63;
  const int col  = lane & 15;
  const int quad = lane >> 4;
  const int wm = (wave & 1) * 64;
  const int wn = (wave >> 1) * 64;
  const int m0 = blockIdx.y * 128;
  const int n0 = blockIdx.x * 128;

  f32x4 acc[4][4];
  #pragma unroll
  for (int i=0;i<4;i++)
    #pragma unroll
    for (int j=0;j<4;j++) acc[i][j] = (f32x4){0.f,0.f,0.f,0.f};

  size_t abase;
  if constexpr(MODE==0){
    int bb = m0 >> 11, tloc = m0 & 2047;
    abase = ((size_t)bb*2050 + tloc) * 128;
  } else {
    abase = (size_t)m0 * K;
  }

  const int sm = tid >> 3;
  const int sk4 = (tid & 7) * 4;
  const int bn = tid >> 2;
  const int bk8 = (tid & 3) * 8;

  for (int k0 = 0; k0 < K; k0 += 32){
    #pragma unroll
    for (int p=0;p<4;p++){
      int m = p*32 + sm;
      const float* A = (const float*)Av;
      float4 v;
      if constexpr(MODE==0){
        v = *(const float4*)(A + abase + (size_t)m*128 + k0 + sk4);
      } else {
        float4 x4 = *(const float4*)(A + abase + (size_t)m*K + k0 + sk4);
        float4 w4 = *(const float4*)(nwp + k0 + sk4);
        float s = rsp[m0 + m];
        v.x = x4.x*s*w4.x; v.y = x4.y*s*w4.y; v.z = x4.z*s*w4.z; v.w = x4.w*s*w4.w;
      }
      bf16x4 o;
      o[0] = (__bf16)v.x; o[1] = (__bf16)v.y; o[2] = (__bf16)v.z; o[3] = (__bf16)v.w;
      *(bf16x4*)&As[m][sk4] = o;
    }
    #pragma unroll
    for (int p=0;p<2;p++){
      int n = p*64 + bn;
      bf16x8 w = *(const bf16x8*)(Wb + (size_t)(n0+n)*K + k0 + bk8);
      *(bf16x8*)&Bs[n][bk8] = w;
    }
    __syncthreads();
    bf16x8 af[4], bfr[4];
    const int fq = quad*8;
    #pragma unroll
    for (int i=0;i<4;i++) af[i]  = *(const bf16x8*)&As[wm + i*16 + col][fq];
    #pragma unroll
    for (int j=0;j<4;j++) bfr[j] = *(const bf16x8*)&Bs[wn + j*16 + col][fq];
    #pragma unroll
    for (int i=0;i<4;i++)
      #pragma unroll
      for (int j=0;j<4;j++)
        acc[i][j] = __builtin_amdgcn_mfma_f32_16x16x32_bf16(af[i], bfr[j], acc[i][j], 0, 0, 0);
    __syncthreads();
  }

  #pragma unroll
  for (int i=0;i<4;i++){
    #pragma unroll
    for (int j=0;j<4;j++){
      int n_l = wn + j*16 + col;
      #pragma unroll
      for (int r=0;r<4;r++){
        int m = m0 + wm + i*16 + quad*4 + r;
        float c = acc[i][j][r];
        if constexpr(MODE==0){
          int n = n0 + n_l;
          out[(size_t)m*DMODEL + n] = fmaxf(c + bias[n], 0.f);
        } else {
          int n = n0 + n_l;
          if (n < DIN) outb[(size_t)m*DIN + n]        = (__bf16)c;
          else         outz[(size_t)m*DIN + n - DIN]  = (__bf16)siluf(c);
        }
      }
    }
  }
}

// ---------------- fused segment front: dwconv+silu -> MFMA x_proj -> vbc/dub -> scanA ----
__global__ __launch_bounds__(256) void k_seg(const __bf16* __restrict__ xi,
    const __bf16* __restrict__ wpb,
    const float* __restrict__ cw, const float* __restrict__ cb,
    const float* __restrict__ dtw, const float* __restrict__ dtb,
    const float* __restrict__ alog,
    float* __restrict__ vbc, unsigned int* __restrict__ dub,
    float* __restrict__ cseg, float* __restrict__ sdtb){
  __shared__ __bf16 sxc[64][264];
  __shared__ float vls[64][68];
  const int tid = threadIdx.x;
  const size_t m0 = (size_t)blockIdx.x * 64;
  const int b = (int)(m0 >> 11);
  const int g = (int)((m0 >> 6) & (NSEG-1));
  const int seq0 = (int)(m0 & 2047);

  // ---- phase 0: depthwise conv(k=4, bf16 in) + silu -> sxc (bf16 LDS only) ----
  {
    const int c4 = (tid & 63) * 4;
    const int tw = tid >> 6;
    float wc[4][4];
    #pragma unroll
    for (int j=0;j<4;j++)
      #pragma unroll
      for (int k=0;k<4;k++) wc[j][k] = cw[(c4+j)*4 + k];
    float4 cb4 = *(const float4*)(cb + c4);
    #pragma unroll
    for (int it=0; it<16; it++){
      int t = it*4 + tw;
      float4 acc = cb4;
      #pragma unroll
      for (int k=0;k<4;k++){
        if (seq0 + t - 3 + k >= 0){
          bf16x4 xv = *(const bf16x4*)(xi + (m0 + t - 3 + k)*DIN + c4);
          acc.x = fmaf(wc[0][k], (float)xv[0], acc.x);
          acc.y = fmaf(wc[1][k], (float)xv[1], acc.y);
          acc.z = fmaf(wc[2][k], (float)xv[2], acc.z);
          acc.w = fmaf(wc[3][k], (float)xv[3], acc.w);
        }
      }
      bf16x4 o;
      o[0]=(__bf16)siluf(acc.x); o[1]=(__bf16)siluf(acc.y);
      o[2]=(__bf16)siluf(acc.z); o[3]=(__bf16)siluf(acc.w);
      *(bf16x4*)&sxc[t][c4] = o;
    }
  }
  __syncthreads();

  // ---- phase 1: MFMA vls[64][64] = sxc[64x256] @ wpb[64x256]^T ----
  {
    const int wave = tid >> 6, lane = tid & 63;
    const int col = lane & 15, quad = lane >> 4;
    const int wn = wave * 16;
    f32x4 acc[4];
    #pragma unroll
    for (int i=0;i<4;i++) acc[i] = (f32x4){0.f,0.f,0.f,0.f};
    #pragma unroll
    for (int kc=0;kc<8;kc++){
      bf16x8 bfr = *(const bf16x8*)(wpb + (size_t)(wn+col)*256 + kc*32 + quad*8);
      #pragma unroll
      for (int mi=0;mi<4;mi++){
        bf16x8 af = *(const bf16x8*)&sxc[mi*16 + col][kc*32 + quad*8];
        acc[mi] = __builtin_amdgcn_mfma_f32_16x16x32_bf16(af, bfr, acc[mi], 0, 0, 0);
      }
    }
    #pragma unroll
    for (int mi=0;mi<4;mi++)
      #pragma unroll
      for (int r=0;r<4;r++)
        vls[mi*16 + quad*4 + r][wn + col] = acc[mi][r];
  }
  __syncthreads();

  // ---- phase 2: write vbc[t][32] = BC only ----
  #pragma unroll
  for (int p=0;p<8;p++){
    int j = p*256 + tid;           // 2048
    int t = j >> 5, i = j & 31;
    vbc[(m0+t)*32 + i] = vls[t][8+i];
  }

  // ---- phase 3: scanA summary; write packed (dt,u) ----
  {
    const int d = tid;
    const float a0 = -fast_exp(alog[d*DST]) * L2E;
    bool fast = true;
    for (int s=1;s<16;s++){
      float as = -fast_exp(alog[d*DST + s]) * L2E;
      fast = fast && (fabsf(as - (float)(s+1)*a0) <= 1e-3f*fabsf(as));
    }
    float4 w8a = *(const float4*)(dtw + d*8);
    float4 w8b = *(const float4*)(dtw + d*8 + 4);
    const float bd = dtb[d];
    float h0=0.f,h1=0.f,h2=0.f,h3=0.f,h4=0.f,h5=0.f,h6=0.f,h7=0.f;
    float h8=0.f,h9=0.f,h10=0.f,h11=0.f,h12=0.f,h13=0.f,h14=0.f,h15=0.f;
    float ssum = 0.f;
    if (fast){
      for (int t=0;t<SEG;t++){
        float4 v0 = *(const float4*)&vls[t][0];
        float4 v1 = *(const float4*)&vls[t][4];
        float lin = bd;
        lin = fmaf(v0.x,w8a.x, fmaf(v0.y,w8a.y, fmaf(v0.z,w8a.z, fmaf(v0.w,w8a.w, lin))));
        lin = fmaf(v1.x,w8b.x, fmaf(v1.y,w8b.y, fmaf(v1.z,w8b.z, fmaf(v1.w,w8b.w, lin))));
        float dt = softplusf(lin);
        ssum += dt;
        float u = (float)sxc[t][d];
        dub[(m0+t)*DIN + d] = packdu(dt, u);
        float du = dt*u;
        float r1 = fexp2(dt*a0);
        POWTREE(r1)
        float4 q0 = *(const float4*)&vls[t][8];
        float4 q1 = *(const float4*)&vls[t][12];
        float4 q2 = *(const float4*)&vls[t][16];
        float4 q3 = *(const float4*)&vls[t][20];
        float4 q4 = *(const float4*)&vls[t][24];
        float4 q5 = *(const float4*)&vls[t][28];
        float4 q6 = *(const float4*)&vls[t][32];
        float4 q7 = *(const float4*)&vls[t][36];
        h0 =fmaf(r1 ,h0 ,du*q0.x); h1 =fmaf(r2 ,h1 ,du*q0.z);
        h2 =fmaf(r3 ,h2 ,du*q1.x); h3 =fmaf(r4 ,h3 ,du*q1.z);
        h4 =fmaf(r5 ,h4 ,du*q2.x); h5 =fmaf(r6 ,h5 ,du*q2.z);
        h6 =fmaf(r7 ,h6 ,du*q3.x); h7 =fmaf(r8 ,h7 ,du*q3.z);
        h8 =fmaf(r9 ,h8 ,du*q4.x); h9 =fmaf(r10,h9 ,du*q4.z);
        h10=fmaf(r11,h10,du*q5.x); h11=fmaf(r12,h11,du*q5.z);
        h12=fmaf(r13,h12,du*q6.x); h13=fmaf(r14,h13,du*q6.z);
        h14=fmaf(r15,h14,du*q7.x); h15=fmaf(r16,h15,du*q7.z);
      }
    } else {
      for (int t=0;t<SEG;t++){
        float4 v0 = *(const float4*)&vls[t][0];
        float4 v1 = *(const float4*)&vls[t][4];
        float lin = bd;
        lin = fmaf(v0.x,w8a.x, fmaf(v0.y,w8a.y, fmaf(v0.z,w8a.z, fmaf(v0.w,w8a.w, lin))));
        lin = fmaf(v1.x,w8b.x, fmaf(v1.y,w8b.y, fmaf(v1.z,w8b.z, fmaf(v1.w,w8b.w, lin))));
        float dt = softplusf(lin);
        ssum += dt;
        float u = (float)sxc[t][d];
        dub[(m0+t)*DIN + d] = packdu(dt, u);
        float du = dt*u;
        float4 q0 = *(const float4*)&vls[t][8];
        float4 q1 = *(const float4*)&vls[t][12];
        float4 q2 = *(const float4*)&vls[t][16];
        float4 q3 = *(const float4*)&vls[t][20];
        float4 q4 = *(const float4*)&vls[t][24];
        float4 q5 = *(const float4*)&vls[t][28];
        float4 q6 = *(const float4*)&vls[t][32];
        float4 q7 = *(const float4*)&vls[t][36];
        SPSA(h0,h1,q0,0,1)   SPSA(h2,h3,q1,2,3)   SPSA(h4,h5,q2,4,5)   SPSA(h6,h7,q3,6,7)
        SPSA(h8,h9,q4,8,9)   SPSA(h10,h11,q5,10,11) SPSA(h12,h13,q6,12,13) SPSA(h14,h15,q7,14,15)
      }
    }
    size_t base = (((size_t)b*NSEG + g)*DIN + d)*DST;
    float4 o;
    o.x=h0; o.y=h1; o.z=h2; o.w=h3;     *(float4*)(cseg + base     ) = o;
    o.x=h4; o.y=h5; o.z=h6; o.w=h7;     *(float4*)(cseg + base +  4) = o;
    o.x=h8; o.y=h9; o.z=h10; o.w=h11;   *(float4*)(cseg + base +  8) = o;
    o.x=h12; o.y=h13; o.z=h14; o.w=h15; *(float4*)(cseg + base + 12) = o;
    sdtb[((size_t)b*NSEG + g)*DIN + d] = ssum;
  }
}

// ---------------- scanB: serial combine over segments ----------------
__global__ __launch_bounds__(256) void k_scanB(float* __restrict__ cseg,
    const float* __restrict__ sdtb, const float* __restrict__ alog){
  int gl = blockIdx.x*256 + threadIdx.x;
  int b   = gl >> 12;
  int rem = gl & 4095;
  int d = rem >> 4, s = rem & 15;
  const float a = -fast_exp(alog[d*DST + s]) * L2E;
  float h = 0.f;
  for (int g=0; g<NSEG; g++){
    size_t base = ((size_t)b*NSEG + g)*DIN;
    float sd = sdtb[base + d];
    size_t ci = (base + d)*DST + s;
    float c = cseg[ci];
    cseg[ci] = h;
    h = fmaf(fexp2(a*sd), h, c);
  }
}

// ---------------- scanC3: scan + gate + out_proj MFMA + residual + next-layer rms ------
__global__ __launch_bounds__(256) void k_scanC3(float* __restrict__ xres,
    const unsigned int* __restrict__ dub, const float* __restrict__ vbc,
    const __bf16* __restrict__ gzb,
    const float* __restrict__ alog, const float* __restrict__ Dpar,
    const float* __restrict__ cseg, const __bf16* __restrict__ wout,
    float* __restrict__ rs){
  __shared__ __bf16 sy[64][264];        // gated y (bf16); later aliased as sx fp32
  __shared__ float svbc[64][32];
  float* sx = (float*)sy;
  const int tid = threadIdx.x;
  const size_t m0 = (size_t)blockIdx.x * 64;
  const int b = (int)(m0 >> 11);
  const int g = (int)((m0 >> 6) & (NSEG-1));

  #pragma unroll
  for (int p=0;p<8;p++){
    int j = p*256 + tid;           // 2048
    int t = j >> 5, i = j & 31;
    svbc[t][i] = vbc[(m0+t)*32 + i];
  }

  // ---- scan phase (thread = channel), serial h-chain + 2-deep prefetch ----
  {
    const int d = tid;
    const float a0 = -fast_exp(alog[d*DST]) * L2E;
    bool fast = true;
    for (int s=1;s<16;s++){
      float as = -fast_exp(alog[d*DST + s]) * L2E;
      fast = fast && (fabsf(as - (float)(s+1)*a0) <= 1e-3f*fabsf(as));
    }
    const float Dv = Dpar[d];
    size_t base = (((size_t)b*NSEG + g)*DIN + d)*DST;
    float4 hv0 = *(const float4*)(cseg + base);
    float4 hv1 = *(const float4*)(cseg + base + 4);
    float4 hv2 = *(const float4*)(cseg + base + 8);
    float4 hv3 = *(const float4*)(cseg + base + 12);
    float h0=hv0.x,h1=hv0.y,h2=hv0.z,h3=hv0.w;
    float h4=hv1.x,h5=hv1.y,h6=hv1.z,h7=hv1.w;
    float h8=hv2.x,h9=hv2.y,h10=hv2.z,h11=hv2.w;
    float h12=hv3.x,h13=hv3.y,h14=hv3.z,h15=hv3.w;
    __syncthreads();   // svbc staged

    if (fast){
      unsigned int w0 = dub[m0*DIN + d];
      unsigned int w1 = dub[(m0+1)*DIN + d];
      float gz0 = (float)gzb[m0*DIN + d];
      float gz1 = (float)gzb[(m0+1)*DIN + d];
      for (int t=0;t<SEG;t++){
        int tn = (t < SEG-2) ? t+2 : SEG-1;
        unsigned int wn_ = dub[(m0+tn)*DIN + d];
        float gzn = (float)gzb[(m0+tn)*DIN + d];
        float u  = __builtin_bit_cast(float, w0 & 0xffff0000u);
        float dt = __builtin_bit_cast(float, w0 << 16);
        float du = dt*u;
        float r1 = fexp2(dt*a0);
        POWTREE(r1)
        float4 q0 = *(const float4*)&svbc[t][0];
        float4 q1 = *(const float4*)&svbc[t][4];
        float4 q2 = *(const float4*)&svbc[t][8];
        float4 q3 = *(const float4*)&svbc[t][12];
        float4 q4 = *(const float4*)&svbc[t][16];
        float4 q5 = *(const float4*)&svbc[t][20];
        float4 q6 = *(const float4*)&svbc[t][24];
        float4 q7 = *(const float4*)&svbc[t][28];
        h0 =fmaf(r1 ,h0 ,du*q0.x); h1 =fmaf(r2 ,h1 ,du*q0.z);
        h2 =fmaf(r3 ,h2 ,du*q1.x); h3 =fmaf(r4 ,h3 ,du*q1.z);
        h4 =fmaf(r5 ,h4 ,du*q2.x); h5 =fmaf(r6 ,h5 ,du*q2.z);
        h6 =fmaf(r7 ,h6 ,du*q3.x); h7 =fmaf(r8 ,h7 ,du*q3.z);
        h8 =fmaf(r9 ,h8 ,du*q4.x); h9 =fmaf(r10,h9 ,du*q4.z);
        h10=fmaf(r11,h10,du*q5.x); h11=fmaf(r12,h11,du*q5.z);
        h12=fmaf(r13,h12,du*q6.x); h13=fmaf(r14,h13,du*q6.z);
        h14=fmaf(r15,h14,du*q7.x); h15=fmaf(r16,h15,du*q7.z);
        float ya = fmaf(h0,q0.y, fmaf(h1,q0.w, fmaf(h2,q1.y, h3*q1.w)));
        float yb = fmaf(h4,q2.y, fmaf(h5,q2.w, fmaf(h6,q3.y, h7*q3.w)));
        float yc = fmaf(h8,q4.y, fmaf(h9,q4.w, fmaf(h10,q5.y, h11*q5.w)));
        float yd = fmaf(h12,q6.y, fmaf(h13,q6.w, fmaf(h14,q7.y, h15*q7.w)));
        float y = (ya+yb)+(yc+yd);
        sy[t][d] = (__bf16)((y + u*Dv) * gz0);
        w0 = w1; w1 = wn_; gz0 = gz1; gz1 = gzn;
      }
    } else {
      for (int t=0;t<SEG;t++){
        unsigned int w = dub[(m0+t)*DIN + d];
        float u  = __builtin_bit_cast(float, w & 0xffff0000u);
        float dt = __builtin_bit_cast(float, w << 16);
        float du = dt*u;
        float y = 0.f;
        float4 q0 = *(const float4*)&svbc[t][0];
        float4 q1 = *(const float4*)&svbc[t][4];
        float4 q2 = *(const float4*)&svbc[t][8];
        float4 q3 = *(const float4*)&svbc[t][12];
        float4 q4 = *(const float4*)&svbc[t][16];
        float4 q5 = *(const float4*)&svbc[t][20];
        float4 q6 = *(const float4*)&svbc[t][24];
        float4 q7 = *(const float4*)&svbc[t][28];
        SPSY(h0,h1,q0,0,1)   SPSY(h2,h3,q1,2,3)   SPSY(h4,h5,q2,4,5)   SPSY(h6,h7,q3,6,7)
        SPSY(h8,h9,q4,8,9)   SPSY(h10,h11,q5,10,11) SPSY(h12,h13,q6,12,13) SPSY(h14,h15,q7,14,15)
        float gz = (float)gzb[(m0+t)*DIN + d];
        sy[t][d] = (__bf16)((y + u*Dv) * gz);
      }
    }
  }
  __syncthreads();   // sy complete

  // ---- out_proj MFMA: newx[64][128] = sy[64x256] @ wout[128x256]^T + xres ----
  const int wave = tid >> 6, lane = tid & 63;
  const int col = lane & 15, quad = lane >> 4;
  const int wn = wave * 32;
  f32x4 acc[4][2];
  #pragma unroll
  for (int i=0;i<4;i++)
    #pragma unroll
    for (int j=0;j<2;j++) acc[i][j] = (f32x4){0.f,0.f,0.f,0.f};
  #pragma unroll
  for (int kc=0;kc<8;kc++){
    bf16x8 bfr0 = *(const bf16x8*)(wout + (size_t)(wn +      col)*256 + kc*32 + quad*8);
    bf16x8 bfr1 = *(const bf16x8*)(wout + (size_t)(wn + 16 + col)*256 + kc*32 + quad*8);
    #pragma unroll
    for (int mi=0;mi<4;mi++){
      bf16x8 af = *(const bf16x8*)&sy[mi*16 + col][kc*32 + quad*8];
      acc[mi][0] = __builtin_amdgcn_mfma_f32_16x16x32_bf16(af, bfr0, acc[mi][0], 0, 0, 0);
      acc[mi][1] = __builtin_amdgcn_mfma_f32_16x16x32_bf16(af, bfr1, acc[mi][1], 0, 0, 0);
    }
  }
  __syncthreads();   // sy reads done; sx may now overwrite

  // ---- epilogue: residual add -> global + LDS(sx); then rms for next layer ----
  #pragma unroll
  for (int mi=0;mi<4;mi++){
    #pragma unroll
    for (int j=0;j<2;j++){
      int n = wn + j*16 + col;
      #pragma unroll
      for (int r=0;r<4;r++){
        int ml = mi*16 + quad*4 + r;
        size_t go = (m0 + ml)*DMODEL + n;
        float nx = xres[go] + acc[mi][j][r];
        xres[go] = nx;
        sx[ml*132 + n] = nx;
      }
    }
  }
  __syncthreads();
  {
    int row = tid >> 2, q = tid & 3;
    const float* pr = sx + row*132 + q*32;
    float ss = 0.f;
    #pragma unroll
    for (int i=0;i<32;i+=4){
      float4 v = *(const float4*)(pr + i);
      ss += v.x*v.x + v.y*v.y + v.z*v.z + v.w*v.w;
    }
    ss += __shfl_xor(ss, 1);
    ss += __shfl_xor(ss, 2);
    if (q == 0) rs[m0 + row] = rsqrtf(ss*(1.f/128.f) + 1e-5f);
  }
}

// ---------------- masked mean pool over a chunk ----------------
__global__ __launch_bounds__(256) void k_pool1(const float* __restrict__ x,
    const float* __restrict__ mask, float* __restrict__ part, float* __restrict__ pmask){
  int b = blockIdx.y, seg = blockIdx.x;
  int d = threadIdx.x & 127, half = threadIdx.x >> 7;
  int t0 = seg*128 + half*64;
  float acc = 0.f, macc = 0.f;
  for (int i=0;i<64;i++){
    int t = t0 + i;
    float mv = mask[(size_t)b*SL + t];
    acc = fmaf(x[((size_t)b*SL + t)*DMODEL + d], mv, acc);
    macc += mv;
  }
  __shared__ float sm[256];
  __shared__ float smm[2];
  sm[threadIdx.x] = acc;
  if (d == 0) smm[half] = macc;
  __syncthreads();
  if (half == 0){
    part[((size_t)b*16 + seg)*128 + d] = sm[d] + sm[128+d];
    if (d == 0) pmask[b*16 + seg] = smm[0] + smm[1];
  }
}

__global__ void k_pool2(const float* __restrict__ part, const float* __restrict__ pmask,
                        float* __restrict__ pooled){
  int b = blockIdx.x, d = threadIdx.x;
  float acc = 0.f, ms = 0.f;
  for (int s=0;s<16;s++){ acc += part[((size_t)b*16+s)*128 + d]; ms += pmask[b*16+s]; }
  pooled[(size_t)b*128 + d] = acc / fmaxf(ms, 1e-9f);
}

// ---------------- tiny MLP ----------------
__global__ void k_mlp_a(const float* __restrict__ in, const float* __restrict__ w,
                        const float* __restrict__ bias, float* __restrict__ out, int K){
  int b = blockIdx.y;
  int n = blockIdx.x*128 + threadIdx.x;
  const float4* pw = (const float4*)(w + (size_t)n*K);
  const float4* pi = (const float4*)(in + (size_t)b*K);
  float acc = 0.f;
  for (int k=0;k<K/4;k++){
    float4 a = pi[k], ww = pw[k];
    acc = fmaf(a.x,ww.x, fmaf(a.y,ww.y, fmaf(a.z,ww.z, fmaf(a.w,ww.w, acc))));
  }
  out[(size_t)b*512 + n] = fmaxf(acc + bias[n], 0.f);
}

__global__ void k_mlp3(const float* __restrict__ h, const float* __restrict__ w,
                       const float* __restrict__ bias, float* __restrict__ out){
  int b = blockIdx.x;
  int n = threadIdx.x >> 6, lane = threadIdx.x & 63;
  if (n >= 3) return;
  float acc = 0.f;
  for (int k=lane; k<512; k+=64) acc = fmaf(h[(size_t)b*512+k], w[(size_t)n*512+k], acc);
  #pragma unroll
  for (int m=1;m<64;m<<=1) acc += __shfl_xor(acc, m);
  if (lane == 0) out[(size_t)b*3 + n] = acc + bias[n];
}

// ---------------- launch ----------------
extern "C" void kernel_launch(void* const* d_in, const int* in_sizes, int n_in,
                              void* d_out, int out_size, void* d_ws, size_t ws_size,
                              hipStream_t stream){
  const int*   tokens = (const int*)  d_in[0];
  const float* mask   = (const float*)d_in[1];
  const float* emb    = (const float*)d_in[2];
  const float* bn_w   = (const float*)d_in[3];
  const float* bn_b   = (const float*)d_in[4];
  const float* conv_w = (const float*)d_in[5];
  const float* conv_b = (const float*)d_in[6];
  const float* in_w   = (const float*)d_in[7];
  const float* c1_w   = (const float*)d_in[8];
  const float* c1_b   = (const float*)d_in[9];
  const float* xp_w   = (const float*)d_in[10];
  const float* dtp_w  = (const float*)d_in[11];
  const float* dtp_b  = (const float*)d_in[12];
  const float* A_log  = (const float*)d_in[13];
  const float* D_par  = (const float*)d_in[14];
  const float* out_w  = (const float*)d_in[15];
  const float* nrm_w  = (const float*)d_in[16];
  const float* l1w = (const float*)d_in[17]; const float* l1b = (const float*)d_in[18];
  const float* l2w = (const float*)d_in[19]; const float* l2b = (const float*)d_in[20];
  const float* l3w = (const float*)d_in[21]; const float* l3b = (const float*)d_in[22];
  float* dout = (float*)d_out;

  // per-token floats: x 128 + rs 1 + xi(bf16) 128 + dub(uint) 256 + vbc 32 + cseg 64
  //                   + sdt 4 + gz(bf16) 128 = 741
  int CB = 64;
  while (CB > 1 && ((size_t)CB*SL*741 + FIX_END)*4 > ws_size) CB >>= 1;
  if (((size_t)CB*SL*741 + FIX_END)*4 > ws_size) return;
  const size_t CTOK = (size_t)CB*SL;

  float* ws  = (float*)d_ws;
  float* pl  = ws + FIX_PL;
  float* pm  = ws + FIX_PM;
  float* pd  = ws + FIX_PD;
  float* h1  = ws + FIX_H1;
  float* h2  = ws + FIX_H2;
  __bf16* wpb   = (__bf16*)(ws + FIX_WP);
  __bf16* w2b   = (__bf16*)(ws + FIX_W2B);
  __bf16* winb  = (__bf16*)(ws + FIX_WINB);
  __bf16* woutb = (__bf16*)(ws + FIX_WOUTB);
  float* xcb = ws + FIX_END;                 // CTOK*128 fp32 residual x
  float* rs  = xcb + CTOK*128;               // CTOK
  __bf16* xib = (__bf16*)(rs + CTOK);        // CTOK*256 bf16 (x-branch)
  unsigned int* dub = (unsigned int*)(xib + CTOK*256);   // CTOK*256 uint (packed dt,u)
  float* pad = (float*)xib;                  // fp32 embed-pad scratch (aliases xib+dub)
  float* vbc = (float*)(dub + CTOK*256);     // CTOK*32 fp32 (interleaved BC)
  float* csg = vbc + CTOK*32;                // CTOK*64
  float* sdt = csg + CTOK*64;                // CTOK*4
  __bf16* zb  = (__bf16*)(sdt + CTOK*4);     // CTOK*256 bf16 (gz)

  k_w2b<<<192, 256, 0, stream>>>(conv_w, w2b);
  k_cvt<<<1024, 256, 0, stream>>>(in_w,  winb,  4*512*128);
  k_cvt<<<512,  256, 0, stream>>>(out_w, woutb, 4*128*256);
  k_wprep<<<256, 256, 0, stream>>>(xp_w, wpb);

  const int nchunks = NB / CB;
  for (int c = 0; c < nchunks; c++){
    const int* tok_c = tokens + (size_t)c*CTOK;

    k_embed<<<CB*2050, 128, 0, stream>>>(tok_c, emb, bn_w, bn_b, pad);
    k_mgemm<0,384,128><<<dim3(1, CTOK/128), 256, 0, stream>>>(
        pad, w2b, conv_b, nullptr, nullptr, xcb, nullptr, nullptr);
    k_rmsscale<<<CTOK/4, 256, 0, stream>>>(xcb, rs);

    for (int layer = 0; layer < NLAYER; layer++){
      const __bf16* lin = winb  + (size_t)layer*512*128;
      const float* lcw  = c1_w  + (size_t)layer*DIN*4;
      const float* lcb  = c1_b  + (size_t)layer*DIN;
      const float* ldw  = dtp_w + (size_t)layer*DIN*8;
      const float* ldb  = dtp_b + (size_t)layer*DIN;
      const float* lal  = A_log + (size_t)layer*DIN*DST;
      const float* lD   = D_par + (size_t)layer*DIN;
      const __bf16* low = woutb + (size_t)layer*128*256;
      const float* lnw  = nrm_w + (size_t)layer*128;

      k_mgemm<1,128,512><<<dim3(4, CTOK/128), 256, 0, stream>>>(
          xcb, lin, nullptr, rs, lnw, nullptr, xib, zb);
      k_seg<<<(int)(CTOK/64), 256, 0, stream>>>(
          xib, wpb + (size_t)layer*64*256, lcw, lcb, ldw, ldb, lal, vbc, dub, csg, sdt);
      k_scanB<<<CB*16, 256, 0, stream>>>(csg, sdt, lal);
      k_scanC3<<<(int)(CTOK/64), 256, 0, stream>>>(
          xcb, dub, vbc, zb, lal, lD, csg, low, rs);
    }

    k_pool1<<<dim3(16, CB), 256, 0, stream>>>(
        xcb, mask + (size_t)c*CTOK, pl + (size_t)c*CB*16*128, pm + (size_t)c*CB*16);
  }

  k_pool2<<<NB, 128, 0, stream>>>(pl, pm, pd);
  k_mlp_a<<<dim3(4, NB), 128, 0, stream>>>(pd, l1w, l1b, h1, 128);
  k_mlp_a<<<dim3(4, NB), 128, 0, stream>>>(h1, l2w, l2b, h2, 512);
  k_mlp3<<<NB, 256, 0, stream>>>(h2, l3w, l3b, dout);
}

// Round 20
// 1512.516 us; speedup vs baseline: 1.0282x; 1.0282x over previous
//
#include <hip/hip_runtime.h>
#include <math.h>

// ---------------- problem constants ----------------
#define NB     64
#define SL     2048
#define NTOK   (NB*SL)
#define EMB_D  128
#define DMODEL 128
#define DIN    256
#define DST    16
#define NLAYER 4
#define SEG    64
#define NSEG   (SL/SEG)        // 32
#define L2E    1.4426950408889634f
#define LN2    0.6931471805599453f

typedef __bf16 bf16x8 __attribute__((ext_vector_type(8)));
typedef __bf16 bf16x4 __attribute__((ext_vector_type(4)));
typedef float  f32x4  __attribute__((ext_vector_type(4)));

// fixed small region (floats)
#define FIX_PL   ((size_t)0)
#define FIX_PM   (FIX_PL + 131072)
#define FIX_PD   (FIX_PM + 1024)
#define FIX_H1   (FIX_PD + 8192)
#define FIX_H2   (FIX_H1 + 32768)
#define FIX_WP   (FIX_H2 + 32768)
#define FIX_W2B  (FIX_WP + 65536)
#define FIX_WINB (FIX_W2B + 24576)
#define FIX_WOUTB (FIX_WINB + 131072)
#define FIX_END  (FIX_WOUTB + 65536)

// raw-instruction transcendentals
__device__ __forceinline__ float fexp2(float x){ return __builtin_amdgcn_exp2f(x); }
__device__ __forceinline__ float flog2(float x){ return __builtin_amdgcn_logf(x); }
__device__ __forceinline__ float frcp (float x){ return __builtin_amdgcn_rcpf(x); }
__device__ __forceinline__ float fast_exp(float x){ return fexp2(x*L2E); }
__device__ __forceinline__ float siluf(float v){ return v * frcp(1.f + fast_exp(-v)); }
__device__ __forceinline__ float softplusf(float a){
  return fmaxf(a,0.f) + flog2(1.f + fexp2(-fabsf(a)*L2E)) * LN2;
}
__device__ __forceinline__ unsigned short bfbits(float x){
  __bf16 b = (__bf16)x; return __builtin_bit_cast(unsigned short, b);
}
__device__ __forceinline__ unsigned int packdu(float dt, float u){
  return ((unsigned int)bfbits(u) << 16) | (unsigned int)bfbits(dt);
}

// exact-path state-pair macros (fallback only)
#define SPSA(hA,hB,q,s0,s1) { float eA=fexp2(dt*(-fast_exp(alog[d*DST+s0])*L2E)); \
                              hA=fmaf(eA,hA,du*q.x); \
                              float eB=fexp2(dt*(-fast_exp(alog[d*DST+s1])*L2E)); \
                              hB=fmaf(eB,hB,du*q.z); }
#define SPSY(hA,hB,q,s0,s1) { float eA=fexp2(dt*(-fast_exp(alog[d*DST+s0])*L2E)); \
                              hA=fmaf(eA,hA,du*q.x); y=fmaf(hA,q.y,y); \
                              float eB=fexp2(dt*(-fast_exp(alog[d*DST+s1])*L2E)); \
                              hB=fmaf(eB,hB,du*q.z); y=fmaf(hB,q.w,y); }

// power tree r^1..r^16 from r (depth 4)
#define POWTREE(r) \
  float r2=(r)*(r), r4=r2*r2, r8=r4*r4; \
  float r3=r2*(r), r5=r4*(r), r6=r4*r2, r7=r4*r3; \
  float r9=r8*(r), r10=r8*r2, r11=r8*r3, r12=r8*r4; \
  float r13=r8*r5, r14=r8*r6, r15=r8*r7, r16=r8*r8;

// ---------------- weight prep ----------------
__global__ void k_w2b(const float* __restrict__ cw, __bf16* __restrict__ w2){
  int g = blockIdx.x*256 + threadIdx.x;
  if (g >= 128*384) return;
  int d = g / 384, j = g % 384;
  int k = j >> 7, e = j & 127;
  w2[d*384 + k*128 + e] = (__bf16)cw[d*384 + e*3 + k];
}

__global__ void k_cvt(const float* __restrict__ src, __bf16* __restrict__ dst, int n){
  int i = blockIdx.x*256 + threadIdx.x;
  if (i < n) dst[i] = (__bf16)src[i];
}

__global__ void k_wprep(const float* __restrict__ xpw, __bf16* __restrict__ wp){
  int g = blockIdx.x*256 + threadIdx.x;      // 65536
  int l = g >> 14, rem = g & 16383;
  int n = rem >> 8, k = rem & 255;
  float v = 0.f;
  if (n < 8){
    v = xpw[(size_t)l*40*256 + n*256 + k];
  } else if (n < 40){
    int i = n - 8;
    int row = 8 + ((i&1)<<4) + (i>>1);
    v = xpw[(size_t)l*40*256 + row*256 + k];
  }
  wp[g] = (__bf16)v;
}

// ---------------- embed + BN into padded chunk buffer (fp32 scratch) ----------------
__global__ void k_embed(const int* __restrict__ tok, const float* __restrict__ emb,
                        const float* __restrict__ bnw, const float* __restrict__ bnb,
                        float* __restrict__ xp){
  int r = blockIdx.x;                 // CB*2050 rows
  int e = threadIdx.x;                // 128
  int b = r / 2050, tp = r % 2050;
  float v = 0.f;
  if (tp != 0 && tp != 2049){
    int t = tp - 1;
    int id = tok[(size_t)b*SL + t];
    float s = bnw[e] * rsqrtf(1.0f + 1e-5f);
    v = emb[(size_t)id*EMB_D + e] * s + bnb[e];
  }
  xp[(size_t)r*EMB_D + e] = v;
}

// ---------------- rmsnorm scale only (after front conv) ----------------
__global__ __launch_bounds__(256) void k_rmsscale(const float* __restrict__ x,
                                                  float* __restrict__ rs){
  int wv = threadIdx.x>>6, lane = threadIdx.x&63;
  size_t tok = (size_t)blockIdx.x*4 + wv;
  float2 v = *(const float2*)(x + tok*128 + lane*2);
  float ss = v.x*v.x + v.y*v.y;
  #pragma unroll
  for (int m=1;m<64;m<<=1) ss += __shfl_xor(ss, m);
  float r = rsqrtf(ss*(1.f/128.f) + 1e-5f);
  if (lane == 0) rs[tok] = r;
}

// ---------------- bf16 MFMA GEMM ----------------
// MODE 0: A fp32 (padded im2col rows), epi relu(+bias) -> out fp32
// MODE 1: A fp32 (x), staged *rs*nw; epi n<256 -> outb (xi bf16), else outz (gz bf16)
template<int MODE, int K, int N>
__global__ __launch_bounds__(256) void k_mgemm(
    const void* __restrict__ Av, const __bf16* __restrict__ Wb,
    const float* __restrict__ bias, const float* __restrict__ rsp,
    const float* __restrict__ nwp,
    float* __restrict__ out, __bf16* __restrict__ outb, __bf16* __restrict__ outz){
  __shared__ __bf16 As[128][40];
  __shared__ __bf16 Bs[128][40];
  const int tid  = threadIdx.x;
  const int wave = tid >> 6;
  const int lane = tid & 63;
  const int col  = lane & 15;
  const int quad = lane >> 4;
  const int wm = (wave & 1) * 64;
  const int wn = (wave >> 1) * 64;
  const int m0 = blockIdx.y * 128;
  const int n0 = blockIdx.x * 128;

  f32x4 acc[4][4];
  #pragma unroll
  for (int i=0;i<4;i++)
    #pragma unroll
    for (int j=0;j<4;j++) acc[i][j] = (f32x4){0.f,0.f,0.f,0.f};

  size_t abase;
  if constexpr(MODE==0){
    int bb = m0 >> 11, tloc = m0 & 2047;
    abase = ((size_t)bb*2050 + tloc) * 128;
  } else {
    abase = (size_t)m0 * K;
  }

  const int sm = tid >> 3;
  const int sk4 = (tid & 7) * 4;
  const int bn = tid >> 2;
  const int bk8 = (tid & 3) * 8;

  for (int k0 = 0; k0 < K; k0 += 32){
    #pragma unroll
    for (int p=0;p<4;p++){
      int m = p*32 + sm;
      const float* A = (const float*)Av;
      float4 v;
      if constexpr(MODE==0){
        v = *(const float4*)(A + abase + (size_t)m*128 + k0 + sk4);
      } else {
        float4 x4 = *(const float4*)(A + abase + (size_t)m*K + k0 + sk4);
        float4 w4 = *(const float4*)(nwp + k0 + sk4);
        float s = rsp[m0 + m];
        v.x = x4.x*s*w4.x; v.y = x4.y*s*w4.y; v.z = x4.z*s*w4.z; v.w = x4.w*s*w4.w;
      }
      bf16x4 o;
      o[0] = (__bf16)v.x; o[1] = (__bf16)v.y; o[2] = (__bf16)v.z; o[3] = (__bf16)v.w;
      *(bf16x4*)&As[m][sk4] = o;
    }
    #pragma unroll
    for (int p=0;p<2;p++){
      int n = p*64 + bn;
      bf16x8 w = *(const bf16x8*)(Wb + (size_t)(n0+n)*K + k0 + bk8);
      *(bf16x8*)&Bs[n][bk8] = w;
    }
    __syncthreads();
    bf16x8 af[4], bfr[4];
    const int fq = quad*8;
    #pragma unroll
    for (int i=0;i<4;i++) af[i]  = *(const bf16x8*)&As[wm + i*16 + col][fq];
    #pragma unroll
    for (int j=0;j<4;j++) bfr[j] = *(const bf16x8*)&Bs[wn + j*16 + col][fq];
    #pragma unroll
    for (int i=0;i<4;i++)
      #pragma unroll
      for (int j=0;j<4;j++)
        acc[i][j] = __builtin_amdgcn_mfma_f32_16x16x32_bf16(af[i], bfr[j], acc[i][j], 0, 0, 0);
    __syncthreads();
  }

  #pragma unroll
  for (int i=0;i<4;i++){
    #pragma unroll
    for (int j=0;j<4;j++){
      int n_l = wn + j*16 + col;
      #pragma unroll
      for (int r=0;r<4;r++){
        int m = m0 + wm + i*16 + quad*4 + r;
        float c = acc[i][j][r];
        if constexpr(MODE==0){
          int n = n0 + n_l;
          out[(size_t)m*DMODEL + n] = fmaxf(c + bias[n], 0.f);
        } else {
          int n = n0 + n_l;
          if (n < DIN) outb[(size_t)m*DIN + n]        = (__bf16)c;
          else         outz[(size_t)m*DIN + n - DIN]  = (__bf16)siluf(c);
        }
      }
    }
  }
}

// ---------------- fused segment front: dwconv+silu -> MFMA x_proj -> vbc/dub -> scanA ----
__global__ __launch_bounds__(256) void k_seg(const __bf16* __restrict__ xi,
    const __bf16* __restrict__ wpb,
    const float* __restrict__ cw, const float* __restrict__ cb,
    const float* __restrict__ dtw, const float* __restrict__ dtb,
    const float* __restrict__ alog,
    float* __restrict__ vbc, unsigned int* __restrict__ dub,
    float* __restrict__ cseg, float* __restrict__ sdtb){
  __shared__ __bf16 sxc[64][264];
  __shared__ float vls[64][68];
  const int tid = threadIdx.x;
  const size_t m0 = (size_t)blockIdx.x * 64;
  const int b = (int)(m0 >> 11);
  const int g = (int)((m0 >> 6) & (NSEG-1));
  const int seq0 = (int)(m0 & 2047);

  // ---- phase 0: depthwise conv(k=4, bf16 in) + silu -> sxc (bf16 LDS only) ----
  {
    const int c4 = (tid & 63) * 4;
    const int tw = tid >> 6;
    float wc[4][4];
    #pragma unroll
    for (int j=0;j<4;j++)
      #pragma unroll
      for (int k=0;k<4;k++) wc[j][k] = cw[(c4+j)*4 + k];
    float4 cb4 = *(const float4*)(cb + c4);
    #pragma unroll
    for (int it=0; it<16; it++){
      int t = it*4 + tw;
      float4 acc = cb4;
      #pragma unroll
      for (int k=0;k<4;k++){
        if (seq0 + t - 3 + k >= 0){
          bf16x4 xv = *(const bf16x4*)(xi + (m0 + t - 3 + k)*DIN + c4);
          acc.x = fmaf(wc[0][k], (float)xv[0], acc.x);
          acc.y = fmaf(wc[1][k], (float)xv[1], acc.y);
          acc.z = fmaf(wc[2][k], (float)xv[2], acc.z);
          acc.w = fmaf(wc[3][k], (float)xv[3], acc.w);
        }
      }
      bf16x4 o;
      o[0]=(__bf16)siluf(acc.x); o[1]=(__bf16)siluf(acc.y);
      o[2]=(__bf16)siluf(acc.z); o[3]=(__bf16)siluf(acc.w);
      *(bf16x4*)&sxc[t][c4] = o;
    }
  }
  __syncthreads();

  // ---- phase 1: MFMA vls[64][64] = sxc[64x256] @ wpb[64x256]^T ----
  {
    const int wave = tid >> 6, lane = tid & 63;
    const int col = lane & 15, quad = lane >> 4;
    const int wn = wave * 16;
    f32x4 acc[4];
    #pragma unroll
    for (int i=0;i<4;i++) acc[i] = (f32x4){0.f,0.f,0.f,0.f};
    #pragma unroll
    for (int kc=0;kc<8;kc++){
      bf16x8 bfr = *(const bf16x8*)(wpb + (size_t)(wn+col)*256 + kc*32 + quad*8);
      #pragma unroll
      for (int mi=0;mi<4;mi++){
        bf16x8 af = *(const bf16x8*)&sxc[mi*16 + col][kc*32 + quad*8];
        acc[mi] = __builtin_amdgcn_mfma_f32_16x16x32_bf16(af, bfr, acc[mi], 0, 0, 0);
      }
    }
    #pragma unroll
    for (int mi=0;mi<4;mi++)
      #pragma unroll
      for (int r=0;r<4;r++)
        vls[mi*16 + quad*4 + r][wn + col] = acc[mi][r];
  }
  __syncthreads();

  // ---- phase 2: write vbc[t][32] = BC only ----
  #pragma unroll
  for (int p=0;p<8;p++){
    int j = p*256 + tid;           // 2048
    int t = j >> 5, i = j & 31;
    vbc[(m0+t)*32 + i] = vls[t][8+i];
  }

  // ---- phase 3: scanA summary; write packed (dt,u) ----
  {
    const int d = tid;
    const float a0 = -fast_exp(alog[d*DST]) * L2E;
    bool fast = true;
    for (int s=1;s<16;s++){
      float as = -fast_exp(alog[d*DST + s]) * L2E;
      fast = fast && (fabsf(as - (float)(s+1)*a0) <= 1e-3f*fabsf(as));
    }
    float4 w8a = *(const float4*)(dtw + d*8);
    float4 w8b = *(const float4*)(dtw + d*8 + 4);
    const float bd = dtb[d];
    float h0=0.f,h1=0.f,h2=0.f,h3=0.f,h4=0.f,h5=0.f,h6=0.f,h7=0.f;
    float h8=0.f,h9=0.f,h10=0.f,h11=0.f,h12=0.f,h13=0.f,h14=0.f,h15=0.f;
    float ssum = 0.f;
    if (fast){
      for (int t=0;t<SEG;t++){
        float4 v0 = *(const float4*)&vls[t][0];
        float4 v1 = *(const float4*)&vls[t][4];
        float lin = bd;
        lin = fmaf(v0.x,w8a.x, fmaf(v0.y,w8a.y, fmaf(v0.z,w8a.z, fmaf(v0.w,w8a.w, lin))));
        lin = fmaf(v1.x,w8b.x, fmaf(v1.y,w8b.y, fmaf(v1.z,w8b.z, fmaf(v1.w,w8b.w, lin))));
        float dt = softplusf(lin);
        ssum += dt;
        float u = (float)sxc[t][d];
        dub[(m0+t)*DIN + d] = packdu(dt, u);
        float du = dt*u;
        float r1 = fexp2(dt*a0);
        POWTREE(r1)
        float4 q0 = *(const float4*)&vls[t][8];
        float4 q1 = *(const float4*)&vls[t][12];
        float4 q2 = *(const float4*)&vls[t][16];
        float4 q3 = *(const float4*)&vls[t][20];
        float4 q4 = *(const float4*)&vls[t][24];
        float4 q5 = *(const float4*)&vls[t][28];
        float4 q6 = *(const float4*)&vls[t][32];
        float4 q7 = *(const float4*)&vls[t][36];
        h0 =fmaf(r1 ,h0 ,du*q0.x); h1 =fmaf(r2 ,h1 ,du*q0.z);
        h2 =fmaf(r3 ,h2 ,du*q1.x); h3 =fmaf(r4 ,h3 ,du*q1.z);
        h4 =fmaf(r5 ,h4 ,du*q2.x); h5 =fmaf(r6 ,h5 ,du*q2.z);
        h6 =fmaf(r7 ,h6 ,du*q3.x); h7 =fmaf(r8 ,h7 ,du*q3.z);
        h8 =fmaf(r9 ,h8 ,du*q4.x); h9 =fmaf(r10,h9 ,du*q4.z);
        h10=fmaf(r11,h10,du*q5.x); h11=fmaf(r12,h11,du*q5.z);
        h12=fmaf(r13,h12,du*q6.x); h13=fmaf(r14,h13,du*q6.z);
        h14=fmaf(r15,h14,du*q7.x); h15=fmaf(r16,h15,du*q7.z);
      }
    } else {
      for (int t=0;t<SEG;t++){
        float4 v0 = *(const float4*)&vls[t][0];
        float4 v1 = *(const float4*)&vls[t][4];
        float lin = bd;
        lin = fmaf(v0.x,w8a.x, fmaf(v0.y,w8a.y, fmaf(v0.z,w8a.z, fmaf(v0.w,w8a.w, lin))));
        lin = fmaf(v1.x,w8b.x, fmaf(v1.y,w8b.y, fmaf(v1.z,w8b.z, fmaf(v1.w,w8b.w, lin))));
        float dt = softplusf(lin);
        ssum += dt;
        float u = (float)sxc[t][d];
        dub[(m0+t)*DIN + d] = packdu(dt, u);
        float du = dt*u;
        float4 q0 = *(const float4*)&vls[t][8];
        float4 q1 = *(const float4*)&vls[t][12];
        float4 q2 = *(const float4*)&vls[t][16];
        float4 q3 = *(const float4*)&vls[t][20];
        float4 q4 = *(const float4*)&vls[t][24];
        float4 q5 = *(const float4*)&vls[t][28];
        float4 q6 = *(const float4*)&vls[t][32];
        float4 q7 = *(const float4*)&vls[t][36];
        SPSA(h0,h1,q0,0,1)   SPSA(h2,h3,q1,2,3)   SPSA(h4,h5,q2,4,5)   SPSA(h6,h7,q3,6,7)
        SPSA(h8,h9,q4,8,9)   SPSA(h10,h11,q5,10,11) SPSA(h12,h13,q6,12,13) SPSA(h14,h15,q7,14,15)
      }
    }
    size_t base = (((size_t)b*NSEG + g)*DIN + d)*DST;
    float4 o;
    o.x=h0; o.y=h1; o.z=h2; o.w=h3;     *(float4*)(cseg + base     ) = o;
    o.x=h4; o.y=h5; o.z=h6; o.w=h7;     *(float4*)(cseg + base +  4) = o;
    o.x=h8; o.y=h9; o.z=h10; o.w=h11;   *(float4*)(cseg + base +  8) = o;
    o.x=h12; o.y=h13; o.z=h14; o.w=h15; *(float4*)(cseg + base + 12) = o;
    sdtb[((size_t)b*NSEG + g)*DIN + d] = ssum;
  }
}

// ---------------- scanB: serial combine over segments ----------------
__global__ __launch_bounds__(256) void k_scanB(float* __restrict__ cseg,
    const float* __restrict__ sdtb, const float* __restrict__ alog){
  int gl = blockIdx.x*256 + threadIdx.x;
  int b   = gl >> 12;
  int rem = gl & 4095;
  int d = rem >> 4, s = rem & 15;
  const float a = -fast_exp(alog[d*DST + s]) * L2E;
  float h = 0.f;
  for (int g=0; g<NSEG; g++){
    size_t base = ((size_t)b*NSEG + g)*DIN;
    float sd = sdtb[base + d];
    size_t ci = (base + d)*DST + s;
    float c = cseg[ci];
    cseg[ci] = h;
    h = fmaf(fexp2(a*sd), h, c);
  }
}

// ---------------- scanC3: scan + gate + out_proj MFMA + residual + next-layer rms ------
__global__ __launch_bounds__(256) void k_scanC3(float* __restrict__ xres,
    const unsigned int* __restrict__ dub, const float* __restrict__ vbc,
    const __bf16* __restrict__ gzb,
    const float* __restrict__ alog, const float* __restrict__ Dpar,
    const float* __restrict__ cseg, const __bf16* __restrict__ wout,
    float* __restrict__ rs){
  __shared__ __bf16 sy[64][264];        // gated y (bf16); later aliased as sx fp32
  __shared__ float svbc[64][32];
  float* sx = (float*)sy;
  const int tid = threadIdx.x;
  const size_t m0 = (size_t)blockIdx.x * 64;
  const int b = (int)(m0 >> 11);
  const int g = (int)((m0 >> 6) & (NSEG-1));

  #pragma unroll
  for (int p=0;p<8;p++){
    int j = p*256 + tid;           // 2048
    int t = j >> 5, i = j & 31;
    svbc[t][i] = vbc[(m0+t)*32 + i];
  }

  // ---- scan phase (thread = channel), serial h-chain + 1-deep prefetch ----
  {
    const int d = tid;
    const float a0 = -fast_exp(alog[d*DST]) * L2E;
    bool fast = true;
    for (int s=1;s<16;s++){
      float as = -fast_exp(alog[d*DST + s]) * L2E;
      fast = fast && (fabsf(as - (float)(s+1)*a0) <= 1e-3f*fabsf(as));
    }
    const float Dv = Dpar[d];
    size_t base = (((size_t)b*NSEG + g)*DIN + d)*DST;
    float4 hv0 = *(const float4*)(cseg + base);
    float4 hv1 = *(const float4*)(cseg + base + 4);
    float4 hv2 = *(const float4*)(cseg + base + 8);
    float4 hv3 = *(const float4*)(cseg + base + 12);
    float h0=hv0.x,h1=hv0.y,h2=hv0.z,h3=hv0.w;
    float h4=hv1.x,h5=hv1.y,h6=hv1.z,h7=hv1.w;
    float h8=hv2.x,h9=hv2.y,h10=hv2.z,h11=hv2.w;
    float h12=hv3.x,h13=hv3.y,h14=hv3.z,h15=hv3.w;
    __syncthreads();   // svbc staged

    if (fast){
      unsigned int w = dub[m0*DIN + d];
      float gz = (float)gzb[m0*DIN + d];
      for (int t=0;t<SEG;t++){
        int tn = (t < SEG-1) ? t+1 : t;
        unsigned int wn_ = dub[(m0+tn)*DIN + d];
        float gzn = (float)gzb[(m0+tn)*DIN + d];
        float u  = __builtin_bit_cast(float, w & 0xffff0000u);
        float dt = __builtin_bit_cast(float, w << 16);
        float du = dt*u;
        float r1 = fexp2(dt*a0);
        POWTREE(r1)
        float4 q0 = *(const float4*)&svbc[t][0];
        float4 q1 = *(const float4*)&svbc[t][4];
        float4 q2 = *(const float4*)&svbc[t][8];
        float4 q3 = *(const float4*)&svbc[t][12];
        float4 q4 = *(const float4*)&svbc[t][16];
        float4 q5 = *(const float4*)&svbc[t][20];
        float4 q6 = *(const float4*)&svbc[t][24];
        float4 q7 = *(const float4*)&svbc[t][28];
        h0 =fmaf(r1 ,h0 ,du*q0.x); h1 =fmaf(r2 ,h1 ,du*q0.z);
        h2 =fmaf(r3 ,h2 ,du*q1.x); h3 =fmaf(r4 ,h3 ,du*q1.z);
        h4 =fmaf(r5 ,h4 ,du*q2.x); h5 =fmaf(r6 ,h5 ,du*q2.z);
        h6 =fmaf(r7 ,h6 ,du*q3.x); h7 =fmaf(r8 ,h7 ,du*q3.z);
        h8 =fmaf(r9 ,h8 ,du*q4.x); h9 =fmaf(r10,h9 ,du*q4.z);
        h10=fmaf(r11,h10,du*q5.x); h11=fmaf(r12,h11,du*q5.z);
        h12=fmaf(r13,h12,du*q6.x); h13=fmaf(r14,h13,du*q6.z);
        h14=fmaf(r15,h14,du*q7.x); h15=fmaf(r16,h15,du*q7.z);
        float ya = fmaf(h0,q0.y, fmaf(h1,q0.w, fmaf(h2,q1.y, h3*q1.w)));
        float yb = fmaf(h4,q2.y, fmaf(h5,q2.w, fmaf(h6,q3.y, h7*q3.w)));
        float yc = fmaf(h8,q4.y, fmaf(h9,q4.w, fmaf(h10,q5.y, h11*q5.w)));
        float yd = fmaf(h12,q6.y, fmaf(h13,q6.w, fmaf(h14,q7.y, h15*q7.w)));
        float y = (ya+yb)+(yc+yd);
        sy[t][d] = (__bf16)((y + u*Dv) * gz);
        w = wn_; gz = gzn;
      }
    } else {
      for (int t=0;t<SEG;t++){
        unsigned int w = dub[(m0+t)*DIN + d];
        float u  = __builtin_bit_cast(float, w & 0xffff0000u);
        float dt = __builtin_bit_cast(float, w << 16);
        float du = dt*u;
        float y = 0.f;
        float4 q0 = *(const float4*)&svbc[t][0];
        float4 q1 = *(const float4*)&svbc[t][4];
        float4 q2 = *(const float4*)&svbc[t][8];
        float4 q3 = *(const float4*)&svbc[t][12];
        float4 q4 = *(const float4*)&svbc[t][16];
        float4 q5 = *(const float4*)&svbc[t][20];
        float4 q6 = *(const float4*)&svbc[t][24];
        float4 q7 = *(const float4*)&svbc[t][28];
        SPSY(h0,h1,q0,0,1)   SPSY(h2,h3,q1,2,3)   SPSY(h4,h5,q2,4,5)   SPSY(h6,h7,q3,6,7)
        SPSY(h8,h9,q4,8,9)   SPSY(h10,h11,q5,10,11) SPSY(h12,h13,q6,12,13) SPSY(h14,h15,q7,14,15)
        float gz = (float)gzb[(m0+t)*DIN + d];
        sy[t][d] = (__bf16)((y + u*Dv) * gz);
      }
    }
  }
  __syncthreads();   // sy complete

  // ---- out_proj MFMA: newx[64][128] = sy[64x256] @ wout[128x256]^T + xres ----
  const int wave = tid >> 6, lane = tid & 63;
  const int col = lane & 15, quad = lane >> 4;
  const int wn = wave * 32;
  f32x4 acc[4][2];
  #pragma unroll
  for (int i=0;i<4;i++)
    #pragma unroll
    for (int j=0;j<2;j++) acc[i][j] = (f32x4){0.f,0.f,0.f,0.f};
  #pragma unroll
  for (int kc=0;kc<8;kc++){
    bf16x8 bfr0 = *(const bf16x8*)(wout + (size_t)(wn +      col)*256 + kc*32 + quad*8);
    bf16x8 bfr1 = *(const bf16x8*)(wout + (size_t)(wn + 16 + col)*256 + kc*32 + quad*8);
    #pragma unroll
    for (int mi=0;mi<4;mi++){
      bf16x8 af = *(const bf16x8*)&sy[mi*16 + col][kc*32 + quad*8];
      acc[mi][0] = __builtin_amdgcn_mfma_f32_16x16x32_bf16(af, bfr0, acc[mi][0], 0, 0, 0);
      acc[mi][1] = __builtin_amdgcn_mfma_f32_16x16x32_bf16(af, bfr1, acc[mi][1], 0, 0, 0);
    }
  }
  __syncthreads();   // sy reads done; sx may now overwrite

  // ---- epilogue: residual add -> global + LDS(sx); then rms for next layer ----
  #pragma unroll
  for (int mi=0;mi<4;mi++){
    #pragma unroll
    for (int j=0;j<2;j++){
      int n = wn + j*16 + col;
      #pragma unroll
      for (int r=0;r<4;r++){
        int ml = mi*16 + quad*4 + r;
        size_t go = (m0 + ml)*DMODEL + n;
        float nx = xres[go] + acc[mi][j][r];
        xres[go] = nx;
        sx[ml*132 + n] = nx;
      }
    }
  }
  __syncthreads();
  {
    int row = tid >> 2, q = tid & 3;
    const float* pr = sx + row*132 + q*32;
    float ss = 0.f;
    #pragma unroll
    for (int i=0;i<32;i+=4){
      float4 v = *(const float4*)(pr + i);
      ss += v.x*v.x + v.y*v.y + v.z*v.z + v.w*v.w;
    }
    ss += __shfl_xor(ss, 1);
    ss += __shfl_xor(ss, 2);
    if (q == 0) rs[m0 + row] = rsqrtf(ss*(1.f/128.f) + 1e-5f);
  }
}

// ---------------- masked mean pool over a chunk ----------------
__global__ __launch_bounds__(256) void k_pool1(const float* __restrict__ x,
    const float* __restrict__ mask, float* __restrict__ part, float* __restrict__ pmask){
  int b = blockIdx.y, seg = blockIdx.x;
  int d = threadIdx.x & 127, half = threadIdx.x >> 7;
  int t0 = seg*128 + half*64;
  float acc = 0.f, macc = 0.f;
  for (int i=0;i<64;i++){
    int t = t0 + i;
    float mv = mask[(size_t)b*SL + t];
    acc = fmaf(x[((size_t)b*SL + t)*DMODEL + d], mv, acc);
    macc += mv;
  }
  __shared__ float sm[256];
  __shared__ float smm[2];
  sm[threadIdx.x] = acc;
  if (d == 0) smm[half] = macc;
  __syncthreads();
  if (half == 0){
    part[((size_t)b*16 + seg)*128 + d] = sm[d] + sm[128+d];
    if (d == 0) pmask[b*16 + seg] = smm[0] + smm[1];
  }
}

__global__ void k_pool2(const float* __restrict__ part, const float* __restrict__ pmask,
                        float* __restrict__ pooled){
  int b = blockIdx.x, d = threadIdx.x;
  float acc = 0.f, ms = 0.f;
  for (int s=0;s<16;s++){ acc += part[((size_t)b*16+s)*128 + d]; ms += pmask[b*16+s]; }
  pooled[(size_t)b*128 + d] = acc / fmaxf(ms, 1e-9f);
}

// ---------------- tiny MLP ----------------
__global__ void k_mlp_a(const float* __restrict__ in, const float* __restrict__ w,
                        const float* __restrict__ bias, float* __restrict__ out, int K){
  int b = blockIdx.y;
  int n = blockIdx.x*128 + threadIdx.x;
  const float4* pw = (const float4*)(w + (size_t)n*K);
  const float4* pi = (const float4*)(in + (size_t)b*K);
  float acc = 0.f;
  for (int k=0;k<K/4;k++){
    float4 a = pi[k], ww = pw[k];
    acc = fmaf(a.x,ww.x, fmaf(a.y,ww.y, fmaf(a.z,ww.z, fmaf(a.w,ww.w, acc))));
  }
  out[(size_t)b*512 + n] = fmaxf(acc + bias[n], 0.f);
}

__global__ void k_mlp3(const float* __restrict__ h, const float* __restrict__ w,
                       const float* __restrict__ bias, float* __restrict__ out){
  int b = blockIdx.x;
  int n = threadIdx.x >> 6, lane = threadIdx.x & 63;
  if (n >= 3) return;
  float acc = 0.f;
  for (int k=lane; k<512; k+=64) acc = fmaf(h[(size_t)b*512+k], w[(size_t)n*512+k], acc);
  #pragma unroll
  for (int m=1;m<64;m<<=1) acc += __shfl_xor(acc, m);
  if (lane == 0) out[(size_t)b*3 + n] = acc + bias[n];
}

// ---------------- launch ----------------
extern "C" void kernel_launch(void* const* d_in, const int* in_sizes, int n_in,
                              void* d_out, int out_size, void* d_ws, size_t ws_size,
                              hipStream_t stream){
  const int*   tokens = (const int*)  d_in[0];
  const float* mask   = (const float*)d_in[1];
  const float* emb    = (const float*)d_in[2];
  const float* bn_w   = (const float*)d_in[3];
  const float* bn_b   = (const float*)d_in[4];
  const float* conv_w = (const float*)d_in[5];
  const float* conv_b = (const float*)d_in[6];
  const float* in_w   = (const float*)d_in[7];
  const float* c1_w   = (const float*)d_in[8];
  const float* c1_b   = (const float*)d_in[9];
  const float* xp_w   = (const float*)d_in[10];
  const float* dtp_w  = (const float*)d_in[11];
  const float* dtp_b  = (const float*)d_in[12];
  const float* A_log  = (const float*)d_in[13];
  const float* D_par  = (const float*)d_in[14];
  const float* out_w  = (const float*)d_in[15];
  const float* nrm_w  = (const float*)d_in[16];
  const float* l1w = (const float*)d_in[17]; const float* l1b = (const float*)d_in[18];
  const float* l2w = (const float*)d_in[19]; const float* l2b = (const float*)d_in[20];
  const float* l3w = (const float*)d_in[21]; const float* l3b = (const float*)d_in[22];
  float* dout = (float*)d_out;

  // per-token floats: x 128 + rs 1 + xi(bf16) 128 + dub(uint) 256 + vbc 32 + cseg 64
  //                   + sdt 4 + gz(bf16) 128 = 741
  int CB = 64;
  while (CB > 1 && ((size_t)CB*SL*741 + FIX_END)*4 > ws_size) CB >>= 1;
  if (((size_t)CB*SL*741 + FIX_END)*4 > ws_size) return;
  const size_t CTOK = (size_t)CB*SL;

  float* ws  = (float*)d_ws;
  float* pl  = ws + FIX_PL;
  float* pm  = ws + FIX_PM;
  float* pd  = ws + FIX_PD;
  float* h1  = ws + FIX_H1;
  float* h2  = ws + FIX_H2;
  __bf16* wpb   = (__bf16*)(ws + FIX_WP);
  __bf16* w2b   = (__bf16*)(ws + FIX_W2B);
  __bf16* winb  = (__bf16*)(ws + FIX_WINB);
  __bf16* woutb = (__bf16*)(ws + FIX_WOUTB);
  float* xcb = ws + FIX_END;                 // CTOK*128 fp32 residual x
  float* rs  = xcb + CTOK*128;               // CTOK
  __bf16* xib = (__bf16*)(rs + CTOK);        // CTOK*256 bf16 (x-branch)
  unsigned int* dub = (unsigned int*)(xib + CTOK*256);   // CTOK*256 uint (packed dt,u)
  float* pad = (float*)xib;                  // fp32 embed-pad scratch (aliases xib+dub)
  float* vbc = (float*)(dub + CTOK*256);     // CTOK*32 fp32 (interleaved BC)
  float* csg = vbc + CTOK*32;                // CTOK*64
  float* sdt = csg + CTOK*64;                // CTOK*4
  __bf16* zb  = (__bf16*)(sdt + CTOK*4);     // CTOK*256 bf16 (gz)

  k_w2b<<<192, 256, 0, stream>>>(conv_w, w2b);
  k_cvt<<<1024, 256, 0, stream>>>(in_w,  winb,  4*512*128);
  k_cvt<<<512,  256, 0, stream>>>(out_w, woutb, 4*128*256);
  k_wprep<<<256, 256, 0, stream>>>(xp_w, wpb);

  const int nchunks = NB / CB;
  for (int c = 0; c < nchunks; c++){
    const int* tok_c = tokens + (size_t)c*CTOK;

    k_embed<<<CB*2050, 128, 0, stream>>>(tok_c, emb, bn_w, bn_b, pad);
    k_mgemm<0,384,128><<<dim3(1, CTOK/128), 256, 0, stream>>>(
        pad, w2b, conv_b, nullptr, nullptr, xcb, nullptr, nullptr);
    k_rmsscale<<<CTOK/4, 256, 0, stream>>>(xcb, rs);

    for (int layer = 0; layer < NLAYER; layer++){
      const __bf16* lin = winb  + (size_t)layer*512*128;
      const float* lcw  = c1_w  + (size_t)layer*DIN*4;
      const float* lcb  = c1_b  + (size_t)layer*DIN;
      const float* ldw  = dtp_w + (size_t)layer*DIN*8;
      const float* ldb  = dtp_b + (size_t)layer*DIN;
      const float* lal  = A_log + (size_t)layer*DIN*DST;
      const float* lD   = D_par + (size_t)layer*DIN;
      const __bf16* low = woutb + (size_t)layer*128*256;
      const float* lnw  = nrm_w + (size_t)layer*128;

      k_mgemm<1,128,512><<<dim3(4, CTOK/128), 256, 0, stream>>>(
          xcb, lin, nullptr, rs, lnw, nullptr, xib, zb);
      k_seg<<<(int)(CTOK/64), 256, 0, stream>>>(
          xib, wpb + (size_t)layer*64*256, lcw, lcb, ldw, ldb, lal, vbc, dub, csg, sdt);
      k_scanB<<<CB*16, 256, 0, stream>>>(csg, sdt, lal);
      k_scanC3<<<(int)(CTOK/64), 256, 0, stream>>>(
          xcb, dub, vbc, zb, lal, lD, csg, low, rs);
    }

    k_pool1<<<dim3(16, CB), 256, 0, stream>>>(
        xcb, mask + (size_t)c*CTOK, pl + (size_t)c*CB*16*128, pm + (size_t)c*CB*16);
  }

  k_pool2<<<NB, 128, 0, stream>>>(pl, pm, pd);
  k_mlp_a<<<dim3(4, NB), 128, 0, stream>>>(pd, l1w, l1b, h1, 128);
  k_mlp_a<<<dim3(4, NB), 128, 0, stream>>>(h1, l2w, l2b, h2, 512);
  k_mlp3<<<NB, 256, 0, stream>>>(h2, l3w, l3b, dout);
}